// Round 1
// baseline (12831.190 us; speedup 1.0000x reference)
//
#include <hip/hip_runtime.h>
#include <hip/hip_bf16.h>
#include <math.h>

#define BB 64
#define IMG 224
#define PP 16
#define CIN 3
#define DM 192
#define DEPTH 24
#define DSTATE 16
#define DINNER 384
#define DTR 12
#define DCONV 4
#define NP 196              // (224/16)^2
#define RTOT (BB * NP)      // 12544 rows

// ---------------- im2col for patch embed ----------------
__global__ __launch_bounds__(256) void im2col_kernel(const float* __restrict__ img,
                                                     float* __restrict__ col) {
    size_t idx = (size_t)blockIdx.x * 256 + threadIdx.x;
    if (idx >= (size_t)RTOT * 768) return;
    int t = (int)(idx % 768);
    size_t r = idx / 768;
    int l = (int)(r % NP);
    int b = (int)(r / NP);
    int ph = l / 14, pw = l % 14;
    int ci = t / 256, rem = t % 256;
    int i = rem / 16, j = rem % 16;
    col[idx] = img[(((size_t)b * CIN + ci) * IMG + ph * 16 + i) * IMG + pw * 16 + j];
}

// ---------------- generic tiled GEMM: C[M,N] = A[M,K] * B[N,K]^T (+bias[n]) ----------------
__global__ __launch_bounds__(256) void gemm_abt_kernel(const float* __restrict__ A,
                                                       const float* __restrict__ Bm,
                                                       float* __restrict__ C,
                                                       const float* __restrict__ bias,
                                                       int M, int N, int K) {
    const int BM = 64, BN = 64, BK = 16, TM = 4, TN = 4;
    __shared__ float As[BK][BM + 1];
    __shared__ float Bs[BK][BN + 1];
    int tid = threadIdx.x;
    int tr = tid / 16, tc = tid % 16;
    int row0 = blockIdx.y * BM, col0 = blockIdx.x * BN;
    float acc[TM][TN] = {};

    for (int k0 = 0; k0 < K; k0 += BK) {
        for (int i = tid; i < BM * BK; i += 256) {
            int m = i / BK, k = i % BK;
            int gm = row0 + m, gk = k0 + k;
            As[k][m] = (gm < M && gk < K) ? A[(size_t)gm * K + gk] : 0.f;
        }
        for (int i = tid; i < BN * BK; i += 256) {
            int n = i / BK, k = i % BK;
            int gn = col0 + n, gk = k0 + k;
            Bs[k][n] = (gn < N && gk < K) ? Bm[(size_t)gn * K + gk] : 0.f;
        }
        __syncthreads();
#pragma unroll
        for (int k = 0; k < BK; k++) {
            float a[TM], b[TN];
#pragma unroll
            for (int i = 0; i < TM; i++) a[i] = As[k][tr * TM + i];
#pragma unroll
            for (int j = 0; j < TN; j++) b[j] = Bs[k][tc * TN + j];
#pragma unroll
            for (int i = 0; i < TM; i++)
#pragma unroll
                for (int j = 0; j < TN; j++) acc[i][j] += a[i] * b[j];
        }
        __syncthreads();
    }
#pragma unroll
    for (int i = 0; i < TM; i++) {
        int gm = row0 + tr * TM + i;
        if (gm >= M) continue;
#pragma unroll
        for (int j = 0; j < TN; j++) {
            int gn = col0 + tc * TN + j;
            if (gn < N) {
                float v = acc[i][j];
                if (bias) v += bias[gn];
                C[(size_t)gm * N + gn] = v;
            }
        }
    }
}

// ---------------- causal depthwise conv (DCONV=4) + SiLU ----------------
// xs lives in xz buffer (row stride 768, first 384 cols). Writes xc (row stride 384).
__global__ __launch_bounds__(256) void conv_silu_kernel(const float* __restrict__ xz,
                                                        const float* __restrict__ cw,
                                                        const float* __restrict__ cb,
                                                        float* __restrict__ xc) {
    size_t idx = (size_t)blockIdx.x * 256 + threadIdx.x;
    if (idx >= (size_t)RTOT * DINNER) return;
    int e = (int)(idx % DINNER);
    size_t r = idx / DINNER;
    int l = (int)(r % NP);
    size_t b = r / NP;
    const float* w = cw + (size_t)e * DCONV;
    float acc = cb[e];
#pragma unroll
    for (int k = 0; k < DCONV; k++) {
        int ls = l + k - (DCONV - 1);
        if (ls >= 0) acc += xz[(b * NP + ls) * 768 + e] * w[k];
    }
    xc[idx] = acc / (1.f + expf(-acc));   // silu
}

// ---------------- selective scan (dt-proj fused) ----------------
// 4 lanes per (b,d): each owns 4 states; y reduced via shfl_xor.
// Epilogue: y2 = (y + u*D) * silu(z), z from xz buffer cols [384,768).
__global__ __launch_bounds__(256) void scan_kernel(const float* __restrict__ xc,
                                                   const float* __restrict__ proj,
                                                   const float* __restrict__ xz,
                                                   float* __restrict__ y2,
                                                   const float* __restrict__ dtw,
                                                   const float* __restrict__ dtb,
                                                   const float* __restrict__ A_log,
                                                   const float* __restrict__ Dv) {
    int tid = threadIdx.x;
    int sg = tid & 3;        // state group: states sg*4 .. sg*4+3
    int dloc = tid >> 2;     // 0..63
    int d = blockIdx.x * 64 + dloc;
    int b = blockIdx.y;

    float wreg[DTR];
    const float* w = dtw + (size_t)d * DTR;
#pragma unroll
    for (int k = 0; k < DTR; k++) wreg[k] = w[k];
    float dtbv = dtb[d];
    float a[4];
    const float* Al = A_log + (size_t)d * DSTATE + sg * 4;
#pragma unroll
    for (int s = 0; s < 4; s++) a[s] = -expf(Al[s]);
    float Dd = Dv[d];
    float h[4] = {0.f, 0.f, 0.f, 0.f};

    size_t rbase = (size_t)b * NP;
    for (int l = 0; l < NP; l++) {
        size_t r = rbase + l;
        const float* pr = proj + r * 44;
        float dtv = dtbv;
#pragma unroll
        for (int k = 0; k < DTR; k++) dtv += pr[k] * wreg[k];
        dtv = (dtv > 20.f) ? dtv : log1pf(expf(dtv));   // softplus
        float u = xc[r * DINNER + d];
        float y = 0.f;
#pragma unroll
        for (int s = 0; s < 4; s++) {
            float dA = expf(dtv * a[s]);
            h[s] = h[s] * dA + dtv * pr[DTR + sg * 4 + s] * u;
            y += h[s] * pr[DTR + DSTATE + sg * 4 + s];
        }
        y += __shfl_xor(y, 1);
        y += __shfl_xor(y, 2);
        if (sg == 0) {
            float z = xz[r * 768 + DINNER + d];
            float yy = (y + u * Dd) * (z / (1.f + expf(-z)));
            y2[r * DINNER + d] = yy;
        }
    }
}

// ---------------- final layernorm: per-row stats ----------------
__global__ __launch_bounds__(256) void ln_stats_kernel(const float* __restrict__ x,
                                                       float* __restrict__ stats) {
    int r = blockIdx.x * 4 + (threadIdx.x >> 6);
    int lane = threadIdx.x & 63;
    if (r >= RTOT) return;
    float s = 0.f, ss = 0.f;
    for (int c = lane; c < DM; c += 64) {
        float v = x[(size_t)r * DM + c];
        s += v;
        ss += v * v;
    }
#pragma unroll
    for (int o = 32; o > 0; o >>= 1) {
        s += __shfl_down(s, o);
        ss += __shfl_down(ss, o);
    }
    if (lane == 0) {
        float mu = s / (float)DM;
        float var = ss / (float)DM - mu * mu;
        stats[r * 2] = mu;
        stats[r * 2 + 1] = rsqrtf(var + 1e-5f);
    }
}

// ---------------- normalized mean over sequence ----------------
__global__ __launch_bounds__(256) void ln_mean_kernel(const float* __restrict__ x,
                                                      const float* __restrict__ stats,
                                                      const float* __restrict__ nw,
                                                      const float* __restrict__ nb,
                                                      float* __restrict__ out) {
    int idx = blockIdx.x * 256 + threadIdx.x;
    if (idx >= BB * DM) return;
    int c = idx % DM;
    int b = idx / DM;
    float acc = 0.f;
    for (int l = 0; l < NP; l++) {
        size_t r = (size_t)b * NP + l;
        acc += (x[r * DM + c] - stats[r * 2]) * stats[r * 2 + 1];
    }
    out[idx] = acc * (1.f / (float)NP) * nw[c] + nb[c];
}

extern "C" void kernel_launch(void* const* d_in, const int* in_sizes, int n_in,
                              void* d_out, int out_size, void* d_ws, size_t ws_size,
                              hipStream_t stream) {
    const float* img     = (const float*)d_in[0];
    const float* patch_w = (const float*)d_in[1];
    const float* patch_b = (const float*)d_in[2];
    const float* in_w    = (const float*)d_in[3];
    const float* conv_w  = (const float*)d_in[4];
    const float* conv_b  = (const float*)d_in[5];
    const float* xpw     = (const float*)d_in[6];
    const float* dtw     = (const float*)d_in[7];
    const float* dtb     = (const float*)d_in[8];
    const float* A_log   = (const float*)d_in[9];
    const float* Dv      = (const float*)d_in[10];
    const float* outw    = (const float*)d_in[11];
    const float* norm_w  = (const float*)d_in[12];
    const float* norm_b  = (const float*)d_in[13];
    float* out = (float*)d_out;

    float* ws = (float*)d_ws;
    const size_t R = RTOT;
    float* xA    = ws;                 // R*192
    float* xB    = xA + R * DM;        // R*192
    float* xz    = xB + R * DM;        // R*768
    float* xc    = xz + R * 768;       // R*384
    float* proj  = xc + R * DINNER;    // R*44
    float* y2    = proj + R * 44;      // R*384
    float* stats = y2 + R * DINNER;    // R*2

    // patch embed: im2col + GEMM(+bias)
    {
        size_t n = R * 768;
        im2col_kernel<<<dim3((unsigned)((n + 255) / 256)), 256, 0, stream>>>(img, xz);
        gemm_abt_kernel<<<dim3(DM / 64, RTOT / 64), 256, 0, stream>>>(
            xz, patch_w, xA, patch_b, RTOT, DM, 768);
    }

    float* xin = xA;
    float* xout = xB;
    for (int layer = 0; layer < DEPTH; layer++) {
        const float* in_w_l  = in_w + (size_t)layer * 2 * DINNER * DM;
        const float* conv_wl = conv_w + (size_t)layer * DINNER * DCONV;
        const float* conv_bl = conv_b + (size_t)layer * DINNER;
        const float* xpw_l   = xpw + (size_t)layer * (DTR + 2 * DSTATE) * DINNER;
        const float* dtw_l   = dtw + (size_t)layer * DINNER * DTR;
        const float* dtb_l   = dtb + (size_t)layer * DINNER;
        const float* Alog_l  = A_log + (size_t)layer * DINNER * DSTATE;
        const float* Dv_l    = Dv + (size_t)layer * DINNER;
        const float* outw_l  = outw + (size_t)layer * DM * DINNER;

        // xz = x @ in_w^T   (M=12544, N=768, K=192)
        gemm_abt_kernel<<<dim3(768 / 64, RTOT / 64), 256, 0, stream>>>(
            xin, in_w_l, xz, nullptr, RTOT, 2 * DINNER, DM);
        // xc = silu(causal depthwise conv(xs))
        {
            size_t n = R * DINNER;
            conv_silu_kernel<<<dim3((unsigned)((n + 255) / 256)), 256, 0, stream>>>(
                xz, conv_wl, conv_bl, xc);
        }
        // proj = xc @ xpw^T   (N=44, K=384)
        gemm_abt_kernel<<<dim3(1, RTOT / 64), 256, 0, stream>>>(
            xc, xpw_l, proj, nullptr, RTOT, DTR + 2 * DSTATE, DINNER);
        // selective scan (dt-proj + softplus + epilogue fused)
        scan_kernel<<<dim3(DINNER / 64, BB), 256, 0, stream>>>(
            xc, proj, xz, y2, dtw_l, dtb_l, Alog_l, Dv_l);
        // x_next = y2 @ outw^T   (N=192, K=384)
        gemm_abt_kernel<<<dim3(DM / 64, RTOT / 64), 256, 0, stream>>>(
            y2, outw_l, xout, nullptr, RTOT, DM, DINNER);

        float* t = xin; xin = xout; xout = t;
    }

    // final layernorm + mean over sequence
    ln_stats_kernel<<<dim3(RTOT / 4), 256, 0, stream>>>(xin, stats);
    ln_mean_kernel<<<dim3((BB * DM + 255) / 256), 256, 0, stream>>>(
        xin, stats, norm_w, norm_b, out);
}

// Round 2
// 11245.173 us; speedup vs baseline: 1.1410x; 1.1410x over previous
//
#include <hip/hip_runtime.h>
#include <hip/hip_bf16.h>
#include <math.h>

#define BB 64
#define IMG 224
#define PP 16
#define CIN 3
#define DM 192
#define DEPTH 24
#define DSTATE 16
#define DINNER 384
#define DTR 12
#define DCONV 4
#define NP 196              // (224/16)^2
#define RTOT (BB * NP)      // 12544 rows
#define CHUNKS 7
#define LC 28               // NP / CHUNKS

// ---------------- im2col for patch embed ----------------
__global__ __launch_bounds__(256) void im2col_kernel(const float* __restrict__ img,
                                                     float* __restrict__ col) {
    size_t idx = (size_t)blockIdx.x * 256 + threadIdx.x;
    if (idx >= (size_t)RTOT * 768) return;
    int t = (int)(idx % 768);
    size_t r = idx / 768;
    int l = (int)(r % NP);
    int b = (int)(r / NP);
    int ph = l / 14, pw = l % 14;
    int ci = t / 256, rem = t % 256;
    int i = rem / 16, j = rem % 16;
    col[idx] = img[(((size_t)b * CIN + ci) * IMG + ph * 16 + i) * IMG + pw * 16 + j];
}

// ---------------- generic tiled GEMM: C[M,N] = A[M,K](lda) * B[N,K]^T (+bias[n]) ----------------
__global__ __launch_bounds__(256) void gemm_abt_kernel(const float* __restrict__ A, int lda,
                                                       const float* __restrict__ Bm,
                                                       float* __restrict__ C,
                                                       const float* __restrict__ bias,
                                                       int M, int N, int K) {
    const int BM = 64, BN = 64, BK = 16, TM = 4, TN = 4;
    __shared__ float As[BK][BM + 1];
    __shared__ float Bs[BK][BN + 1];
    int tid = threadIdx.x;
    int tr = tid / 16, tc = tid % 16;
    int row0 = blockIdx.y * BM, col0 = blockIdx.x * BN;
    float acc[TM][TN] = {};

    for (int k0 = 0; k0 < K; k0 += BK) {
        for (int i = tid; i < BM * BK; i += 256) {
            int m = i / BK, k = i % BK;
            int gm = row0 + m, gk = k0 + k;
            As[k][m] = (gm < M && gk < K) ? A[(size_t)gm * lda + gk] : 0.f;
        }
        for (int i = tid; i < BN * BK; i += 256) {
            int n = i / BK, k = i % BK;
            int gn = col0 + n, gk = k0 + k;
            Bs[k][n] = (gn < N && gk < K) ? Bm[(size_t)gn * K + gk] : 0.f;
        }
        __syncthreads();
#pragma unroll
        for (int k = 0; k < BK; k++) {
            float a[TM], b[TN];
#pragma unroll
            for (int i = 0; i < TM; i++) a[i] = As[k][tr * TM + i];
#pragma unroll
            for (int j = 0; j < TN; j++) b[j] = Bs[k][tc * TN + j];
#pragma unroll
            for (int i = 0; i < TM; i++)
#pragma unroll
                for (int j = 0; j < TN; j++) acc[i][j] += a[i] * b[j];
        }
        __syncthreads();
    }
#pragma unroll
    for (int i = 0; i < TM; i++) {
        int gm = row0 + tr * TM + i;
        if (gm >= M) continue;
#pragma unroll
        for (int j = 0; j < TN; j++) {
            int gn = col0 + tc * TN + j;
            if (gn < N) {
                float v = acc[i][j];
                if (bias) v += bias[gn];
                C[(size_t)gm * N + gn] = v;
            }
        }
    }
}

// ---------------- causal depthwise conv (DCONV=4) + SiLU ----------------
// xs lives in xz buffer (row stride 768, first 384 cols). Writes xc (row stride 384).
__global__ __launch_bounds__(256) void conv_silu_kernel(const float* __restrict__ xz,
                                                        const float* __restrict__ cw,
                                                        const float* __restrict__ cb,
                                                        float* __restrict__ xc) {
    size_t idx = (size_t)blockIdx.x * 256 + threadIdx.x;
    if (idx >= (size_t)RTOT * DINNER) return;
    int e = (int)(idx % DINNER);
    size_t r = idx / DINNER;
    int l = (int)(r % NP);
    size_t b = r / NP;
    const float* w = cw + (size_t)e * DCONV;
    float acc = cb[e];
#pragma unroll
    for (int k = 0; k < DCONV; k++) {
        int ls = l + k - (DCONV - 1);
        if (ls >= 0) acc += xz[(b * NP + ls) * 768 + e] * w[k];
    }
    xc[idx] = acc / (1.f + expf(-acc));   // silu
}

// ---------------- dt projection + softplus: dt[r,d] = softplus(proj[r,0:12]·dtw[d,:] + dtb[d]) ----------------
__global__ __launch_bounds__(256) void dt_kernel(const float* __restrict__ proj,
                                                 const float* __restrict__ dtw,
                                                 const float* __restrict__ dtb,
                                                 float* __restrict__ dt) {
    int idx = blockIdx.x * 256 + threadIdx.x;
    if (idx >= RTOT * DINNER) return;
    int d = idx % DINNER;
    size_t r = (size_t)idx / DINNER;
    const float* pr = proj + r * 44;
    const float* w = dtw + (size_t)d * DTR;
    float acc = dtb[d];
#pragma unroll
    for (int k = 0; k < DTR; k++) acc += pr[k] * w[k];
    dt[idx] = (acc > 20.f) ? acc : log1pf(expf(acc));   // softplus
}

// ---------------- chunked selective scan ----------------
// Pass A: per (b,d,s,chunk): local scan from h=0; record hEnd and prod(dA).
// Thread map: s = tid&15, d = bx*16 + (tid>>4); grid (24, CHUNKS, B).
__global__ __launch_bounds__(256) void scanA_kernel(const float* __restrict__ xc,
                                                    const float* __restrict__ proj,
                                                    const float* __restrict__ dt,
                                                    const float* __restrict__ A_log,
                                                    float* __restrict__ hEnd,
                                                    float* __restrict__ prodDA) {
    int tid = threadIdx.x;
    int s = tid & 15, dl = tid >> 4;
    int d = blockIdx.x * 16 + dl;
    int c = blockIdx.y, b = blockIdx.z;
    float a = -expf(A_log[(size_t)d * DSTATE + s]);
    float h = 0.f, p = 1.f;
    size_t rbase = (size_t)b * NP + (size_t)c * LC;
    for (int l = 0; l < LC; l++) {
        size_t r = rbase + l;
        float dtv = dt[r * DINNER + d];
        float dA = expf(dtv * a);
        h = h * dA + dtv * proj[r * 44 + DTR + s] * xc[r * DINNER + d];
        p *= dA;
    }
    size_t idx = (((size_t)b * CHUNKS + c) * DINNER + d) * DSTATE + s;
    hEnd[idx] = h;
    prodDA[idx] = p;
}

// Pass B: sequential combine over chunks; writes hInit(c) IN PLACE over prodDA.
__global__ __launch_bounds__(256) void scanB_kernel(const float* __restrict__ hEnd,
                                                    float* __restrict__ prodDA) {
    int idx = blockIdx.x * 256 + threadIdx.x;          // (b, d, s), s fastest
    if (idx >= BB * DINNER * DSTATE) return;
    int b = idx / (DINNER * DSTATE);
    int rem = idx % (DINNER * DSTATE);
    float run = 0.f;
    for (int c = 0; c < CHUNKS; c++) {
        size_t off = ((size_t)b * CHUNKS + c) * (DINNER * DSTATE) + rem;
        float p = prodDA[off];
        float e = hEnd[off];
        prodDA[off] = run;          // hInit for chunk c
        run = run * p + e;
    }
}

// Pass C: rerun local scan from hInit; emit y + fused (y+u*D)*silu(z) epilogue.
// Writes y2 into xz cols [0,384) (row stride 768); reads z from cols [384,768).
__global__ __launch_bounds__(256) void scanC_kernel(const float* __restrict__ xc,
                                                    const float* __restrict__ proj,
                                                    const float* __restrict__ dt,
                                                    const float* __restrict__ hInit,
                                                    const float* __restrict__ A_log,
                                                    const float* __restrict__ Dv,
                                                    float* __restrict__ xz) {
    int tid = threadIdx.x;
    int s = tid & 15, dl = tid >> 4;
    int d = blockIdx.x * 16 + dl;
    int c = blockIdx.y, b = blockIdx.z;
    float a = -expf(A_log[(size_t)d * DSTATE + s]);
    size_t idx = (((size_t)b * CHUNKS + c) * DINNER + d) * DSTATE + s;
    float h = hInit[idx];
    float Dd = Dv[d];
    size_t rbase = (size_t)b * NP + (size_t)c * LC;
    for (int l = 0; l < LC; l++) {
        size_t r = rbase + l;
        float dtv = dt[r * DINNER + d];
        float u = xc[r * DINNER + d];
        float dA = expf(dtv * a);
        h = h * dA + dtv * proj[r * 44 + DTR + s] * u;
        float y = h * proj[r * 44 + DTR + DSTATE + s];
        y += __shfl_xor(y, 1);
        y += __shfl_xor(y, 2);
        y += __shfl_xor(y, 4);
        y += __shfl_xor(y, 8);
        if (s == 0) {
            float z = xz[r * 768 + DINNER + d];
            xz[r * 768 + d] = (y + u * Dd) * (z / (1.f + expf(-z)));
        }
    }
}

// ---------------- final layernorm: per-row stats ----------------
__global__ __launch_bounds__(256) void ln_stats_kernel(const float* __restrict__ x,
                                                       float* __restrict__ stats) {
    int r = blockIdx.x * 4 + (threadIdx.x >> 6);
    int lane = threadIdx.x & 63;
    if (r >= RTOT) return;
    float s = 0.f, ss = 0.f;
    for (int c = lane; c < DM; c += 64) {
        float v = x[(size_t)r * DM + c];
        s += v;
        ss += v * v;
    }
#pragma unroll
    for (int o = 32; o > 0; o >>= 1) {
        s += __shfl_down(s, o);
        ss += __shfl_down(ss, o);
    }
    if (lane == 0) {
        float mu = s / (float)DM;
        float var = ss / (float)DM - mu * mu;
        stats[r * 2] = mu;
        stats[r * 2 + 1] = rsqrtf(var + 1e-5f);
    }
}

// ---------------- normalized mean over sequence ----------------
__global__ __launch_bounds__(256) void ln_mean_kernel(const float* __restrict__ x,
                                                      const float* __restrict__ stats,
                                                      const float* __restrict__ nw,
                                                      const float* __restrict__ nb,
                                                      float* __restrict__ out) {
    int idx = blockIdx.x * 256 + threadIdx.x;
    if (idx >= BB * DM) return;
    int c = idx % DM;
    int b = idx / DM;
    float acc = 0.f;
    for (int l = 0; l < NP; l++) {
        size_t r = (size_t)b * NP + l;
        acc += (x[r * DM + c] - stats[r * 2]) * stats[r * 2 + 1];
    }
    out[idx] = acc * (1.f / (float)NP) * nw[c] + nb[c];
}

extern "C" void kernel_launch(void* const* d_in, const int* in_sizes, int n_in,
                              void* d_out, int out_size, void* d_ws, size_t ws_size,
                              hipStream_t stream) {
    const float* img     = (const float*)d_in[0];
    const float* patch_w = (const float*)d_in[1];
    const float* patch_b = (const float*)d_in[2];
    const float* in_w    = (const float*)d_in[3];
    const float* conv_w  = (const float*)d_in[4];
    const float* conv_b  = (const float*)d_in[5];
    const float* xpw     = (const float*)d_in[6];
    const float* dtw     = (const float*)d_in[7];
    const float* dtb     = (const float*)d_in[8];
    const float* A_log   = (const float*)d_in[9];
    const float* Dv      = (const float*)d_in[10];
    const float* outw    = (const float*)d_in[11];
    const float* norm_w  = (const float*)d_in[12];
    const float* norm_b  = (const float*)d_in[13];
    float* out = (float*)d_out;

    float* ws = (float*)d_ws;
    const size_t R = RTOT;
    float* xA     = ws;                  // R*192
    float* xB     = xA + R * DM;         // R*192
    float* xz     = xB + R * DM;         // R*768   (xs | z; y2 overwrites xs half)
    float* xc     = xz + R * 768;        // R*384
    float* proj   = xc + R * DINNER;     // R*44
    float* dtbuf  = proj + R * 44;       // R*384
    float* hEnd   = dtbuf + R * DINNER;  // B*CHUNKS*384*16
    float* prodDA = hEnd + (size_t)BB * CHUNKS * DINNER * DSTATE;   // same size (becomes hInit)
    float* stats  = prodDA + (size_t)BB * CHUNKS * DINNER * DSTATE; // R*2

    // patch embed: im2col + GEMM(+bias)
    {
        size_t n = R * 768;
        im2col_kernel<<<dim3((unsigned)((n + 255) / 256)), 256, 0, stream>>>(img, xz);
        gemm_abt_kernel<<<dim3(DM / 64, RTOT / 64), 256, 0, stream>>>(
            xz, 768, patch_w, xA, patch_b, RTOT, DM, 768);
    }

    float* xin = xA;
    float* xout = xB;
    for (int layer = 0; layer < DEPTH; layer++) {
        const float* in_w_l  = in_w + (size_t)layer * 2 * DINNER * DM;
        const float* conv_wl = conv_w + (size_t)layer * DINNER * DCONV;
        const float* conv_bl = conv_b + (size_t)layer * DINNER;
        const float* xpw_l   = xpw + (size_t)layer * (DTR + 2 * DSTATE) * DINNER;
        const float* dtw_l   = dtw + (size_t)layer * DINNER * DTR;
        const float* dtb_l   = dtb + (size_t)layer * DINNER;
        const float* Alog_l  = A_log + (size_t)layer * DINNER * DSTATE;
        const float* Dv_l    = Dv + (size_t)layer * DINNER;
        const float* outw_l  = outw + (size_t)layer * DM * DINNER;

        // xz = x @ in_w^T   (M=12544, N=768, K=192)
        gemm_abt_kernel<<<dim3(768 / 64, RTOT / 64), 256, 0, stream>>>(
            xin, DM, in_w_l, xz, nullptr, RTOT, 2 * DINNER, DM);
        // xc = silu(causal depthwise conv(xs))
        {
            size_t n = R * DINNER;
            conv_silu_kernel<<<dim3((unsigned)((n + 255) / 256)), 256, 0, stream>>>(
                xz, conv_wl, conv_bl, xc);
        }
        // proj = xc @ xpw^T   (N=44, K=384)
        gemm_abt_kernel<<<dim3(1, RTOT / 64), 256, 0, stream>>>(
            xc, DINNER, xpw_l, proj, nullptr, RTOT, DTR + 2 * DSTATE, DINNER);
        // dt = softplus(proj[:, :12] @ dtw^T + dtb)
        dt_kernel<<<dim3((RTOT * DINNER + 255) / 256), 256, 0, stream>>>(
            proj, dtw_l, dtb_l, dtbuf);
        // chunked scan: A (local), B (combine), C (apply + epilogue -> xz xs-half)
        scanA_kernel<<<dim3(DINNER / 16, CHUNKS, BB), 256, 0, stream>>>(
            xc, proj, dtbuf, Alog_l, hEnd, prodDA);
        scanB_kernel<<<dim3((BB * DINNER * DSTATE + 255) / 256), 256, 0, stream>>>(
            hEnd, prodDA);
        scanC_kernel<<<dim3(DINNER / 16, CHUNKS, BB), 256, 0, stream>>>(
            xc, proj, dtbuf, prodDA, Alog_l, Dv_l, xz);
        // x_next = y2 @ outw^T   (A = xz with lda=768; N=192, K=384)
        gemm_abt_kernel<<<dim3(DM / 64, RTOT / 64), 256, 0, stream>>>(
            xz, 768, outw_l, xout, nullptr, RTOT, DM, DINNER);

        float* t = xin; xin = xout; xout = t;
    }

    // final layernorm + mean over sequence
    ln_stats_kernel<<<dim3(RTOT / 4), 256, 0, stream>>>(xin, stats);
    ln_mean_kernel<<<dim3((BB * DM + 255) / 256), 256, 0, stream>>>(
        xin, stats, norm_w, norm_b, out);
}

// Round 3
// 8315.624 us; speedup vs baseline: 1.5430x; 1.3523x over previous
//
#include <hip/hip_runtime.h>
#include <hip/hip_bf16.h>
#include <math.h>

#define BB 64
#define IMG 224
#define PP 16
#define CIN 3
#define DM 192
#define DEPTH 24
#define DSTATE 16
#define DINNER 384
#define DTR 12
#define DCONV 4
#define NP 196              // (224/16)^2
#define RTOT (BB * NP)      // 12544 rows
#define CHUNKS 7
#define LC 28               // NP / CHUNKS

// ---------------- im2col for patch embed ----------------
__global__ __launch_bounds__(256) void im2col_kernel(const float* __restrict__ img,
                                                     float* __restrict__ col) {
    size_t idx = (size_t)blockIdx.x * 256 + threadIdx.x;
    if (idx >= (size_t)RTOT * 768) return;
    int t = (int)(idx % 768);
    size_t r = idx / 768;
    int l = (int)(r % NP);
    int b = (int)(r / NP);
    int ph = l / 14, pw = l % 14;
    int ci = t / 256, rem = t % 256;
    int i = rem / 16, j = rem % 16;
    col[idx] = img[(((size_t)b * CIN + ci) * IMG + ph * 16 + i) * IMG + pw * 16 + j];
}

// ---------------- tiled fp32 GEMM: C[M,N] = A[M,K](lda) * B[N,K]^T (+bias) ----------------
// 256 threads = 16x16 grid; micro-tile = RM x RN groups of 4 floats, groups 64 apart.
// BM = 64*RM, BN = 64*RN. Requirements: M % BM == 0, K % 16 == 0, N % 4 == 0.
// LDS rows padded +4 floats: keeps 16B alignment for b128 reads and <=2-way banks.
template<int BM, int BN, int RM, int RN>
__global__ __launch_bounds__(256) void gemm_tile_kernel(const float* __restrict__ A, int lda,
                                                        const float* __restrict__ Bm,
                                                        float* __restrict__ C,
                                                        const float* __restrict__ bias,
                                                        int M, int N, int K) {
    constexpr int BK = 16;
    constexpr int LDA_S = BM + 4;
    constexpr int LDB_S = BN + 4;
    __shared__ float As[BK * LDA_S];
    __shared__ float Bs[BK * LDB_S];
    const int tid = threadIdx.x;
    const int tr = tid / 16, tc = tid % 16;
    const int row0 = blockIdx.y * BM, col0 = blockIdx.x * BN;
    const int lrow = tid / 4;     // 0..63, + g*64
    const int lc4  = tid % 4;     // which float4 along k

    float acc[RM * 4][RN * 4] = {};
    float4 aReg[RM], bReg[RN];

    auto loadG = [&](int k0) {
#pragma unroll
        for (int g = 0; g < RM; g++) {
            int row = g * 64 + lrow;
            aReg[g] = *(const float4*)&A[(size_t)(row0 + row) * lda + k0 + lc4 * 4];
        }
#pragma unroll
        for (int g = 0; g < RN; g++) {
            int n = g * 64 + lrow;
            if (col0 + n < N)
                bReg[g] = *(const float4*)&Bm[(size_t)(col0 + n) * K + k0 + lc4 * 4];
            else
                bReg[g] = make_float4(0.f, 0.f, 0.f, 0.f);
        }
    };
    auto storeLDS = [&]() {
#pragma unroll
        for (int g = 0; g < RM; g++) {
            int row = g * 64 + lrow;
            As[(lc4 * 4 + 0) * LDA_S + row] = aReg[g].x;
            As[(lc4 * 4 + 1) * LDA_S + row] = aReg[g].y;
            As[(lc4 * 4 + 2) * LDA_S + row] = aReg[g].z;
            As[(lc4 * 4 + 3) * LDA_S + row] = aReg[g].w;
        }
#pragma unroll
        for (int g = 0; g < RN; g++) {
            int n = g * 64 + lrow;
            Bs[(lc4 * 4 + 0) * LDB_S + n] = bReg[g].x;
            Bs[(lc4 * 4 + 1) * LDB_S + n] = bReg[g].y;
            Bs[(lc4 * 4 + 2) * LDB_S + n] = bReg[g].z;
            Bs[(lc4 * 4 + 3) * LDB_S + n] = bReg[g].w;
        }
    };

    loadG(0);
    storeLDS();
    __syncthreads();
    for (int k0 = BK;; k0 += BK) {
        const bool has_next = (k0 < K);
        if (has_next) loadG(k0);      // global loads in flight during compute
#pragma unroll
        for (int k = 0; k < BK; k++) {
            float a[RM * 4], b[RN * 4];
#pragma unroll
            for (int g = 0; g < RM; g++)
                *(float4*)&a[g * 4] = *(const float4*)&As[k * LDA_S + g * 64 + tr * 4];
#pragma unroll
            for (int g = 0; g < RN; g++)
                *(float4*)&b[g * 4] = *(const float4*)&Bs[k * LDB_S + g * 64 + tc * 4];
#pragma unroll
            for (int i = 0; i < RM * 4; i++)
#pragma unroll
                for (int j = 0; j < RN * 4; j++)
                    acc[i][j] = fmaf(a[i], b[j], acc[i][j]);
        }
        if (!has_next) break;
        __syncthreads();
        storeLDS();
        __syncthreads();
    }

#pragma unroll
    for (int gi = 0; gi < RM; gi++)
#pragma unroll
        for (int i = 0; i < 4; i++) {
            int gm = row0 + gi * 64 + tr * 4 + i;
#pragma unroll
            for (int gj = 0; gj < RN; gj++) {
                int gn = col0 + gj * 64 + tc * 4;
                if (gn + 3 < N) {
                    float4 v;
                    v.x = acc[gi * 4 + i][gj * 4 + 0];
                    v.y = acc[gi * 4 + i][gj * 4 + 1];
                    v.z = acc[gi * 4 + i][gj * 4 + 2];
                    v.w = acc[gi * 4 + i][gj * 4 + 3];
                    if (bias) {
                        float4 bv = *(const float4*)&bias[gn];
                        v.x += bv.x; v.y += bv.y; v.z += bv.z; v.w += bv.w;
                    }
                    *(float4*)&C[(size_t)gm * N + gn] = v;
                }
            }
        }
}

// ---------------- causal depthwise conv (DCONV=4) + SiLU ----------------
__global__ __launch_bounds__(256) void conv_silu_kernel(const float* __restrict__ xz,
                                                        const float* __restrict__ cw,
                                                        const float* __restrict__ cb,
                                                        float* __restrict__ xc) {
    size_t idx = (size_t)blockIdx.x * 256 + threadIdx.x;
    if (idx >= (size_t)RTOT * DINNER) return;
    int e = (int)(idx % DINNER);
    size_t r = idx / DINNER;
    int l = (int)(r % NP);
    size_t b = r / NP;
    const float* w = cw + (size_t)e * DCONV;
    float acc = cb[e];
#pragma unroll
    for (int k = 0; k < DCONV; k++) {
        int ls = l + k - (DCONV - 1);
        if (ls >= 0) acc += xz[(b * NP + ls) * 768 + e] * w[k];
    }
    xc[idx] = acc / (1.f + expf(-acc));   // silu
}

// ---------------- dt projection + softplus ----------------
__global__ __launch_bounds__(256) void dt_kernel(const float* __restrict__ proj,
                                                 const float* __restrict__ dtw,
                                                 const float* __restrict__ dtb,
                                                 float* __restrict__ dt) {
    int idx = blockIdx.x * 256 + threadIdx.x;
    if (idx >= RTOT * DINNER) return;
    int d = idx % DINNER;
    size_t r = (size_t)idx / DINNER;
    const float* pr = proj + r * 44;
    const float* w = dtw + (size_t)d * DTR;
    float acc = dtb[d];
#pragma unroll
    for (int k = 0; k < DTR; k++) acc += pr[k] * w[k];
    dt[idx] = (acc > 20.f) ? acc : log1pf(expf(acc));   // softplus
}

// ---------------- chunked selective scan ----------------
__global__ __launch_bounds__(256) void scanA_kernel(const float* __restrict__ xc,
                                                    const float* __restrict__ proj,
                                                    const float* __restrict__ dt,
                                                    const float* __restrict__ A_log,
                                                    float* __restrict__ hEnd,
                                                    float* __restrict__ prodDA) {
    int tid = threadIdx.x;
    int s = tid & 15, dl = tid >> 4;
    int d = blockIdx.x * 16 + dl;
    int c = blockIdx.y, b = blockIdx.z;
    float a = -expf(A_log[(size_t)d * DSTATE + s]);
    float h = 0.f, p = 1.f;
    size_t rbase = (size_t)b * NP + (size_t)c * LC;
    for (int l = 0; l < LC; l++) {
        size_t r = rbase + l;
        float dtv = dt[r * DINNER + d];
        float dA = expf(dtv * a);
        h = h * dA + dtv * proj[r * 44 + DTR + s] * xc[r * DINNER + d];
        p *= dA;
    }
    size_t idx = (((size_t)b * CHUNKS + c) * DINNER + d) * DSTATE + s;
    hEnd[idx] = h;
    prodDA[idx] = p;
}

__global__ __launch_bounds__(256) void scanB_kernel(const float* __restrict__ hEnd,
                                                    float* __restrict__ prodDA) {
    int idx = blockIdx.x * 256 + threadIdx.x;
    if (idx >= BB * DINNER * DSTATE) return;
    int b = idx / (DINNER * DSTATE);
    int rem = idx % (DINNER * DSTATE);
    float run = 0.f;
    for (int c = 0; c < CHUNKS; c++) {
        size_t off = ((size_t)b * CHUNKS + c) * (DINNER * DSTATE) + rem;
        float p = prodDA[off];
        float e = hEnd[off];
        prodDA[off] = run;          // hInit for chunk c
        run = run * p + e;
    }
}

__global__ __launch_bounds__(256) void scanC_kernel(const float* __restrict__ xc,
                                                    const float* __restrict__ proj,
                                                    const float* __restrict__ dt,
                                                    const float* __restrict__ hInit,
                                                    const float* __restrict__ A_log,
                                                    const float* __restrict__ Dv,
                                                    float* __restrict__ xz) {
    int tid = threadIdx.x;
    int s = tid & 15, dl = tid >> 4;
    int d = blockIdx.x * 16 + dl;
    int c = blockIdx.y, b = blockIdx.z;
    float a = -expf(A_log[(size_t)d * DSTATE + s]);
    size_t idx = (((size_t)b * CHUNKS + c) * DINNER + d) * DSTATE + s;
    float h = hInit[idx];
    float Dd = Dv[d];
    size_t rbase = (size_t)b * NP + (size_t)c * LC;
    for (int l = 0; l < LC; l++) {
        size_t r = rbase + l;
        float dtv = dt[r * DINNER + d];
        float u = xc[r * DINNER + d];
        float dA = expf(dtv * a);
        h = h * dA + dtv * proj[r * 44 + DTR + s] * u;
        float y = h * proj[r * 44 + DTR + DSTATE + s];
        y += __shfl_xor(y, 1);
        y += __shfl_xor(y, 2);
        y += __shfl_xor(y, 4);
        y += __shfl_xor(y, 8);
        if (s == 0) {
            float z = xz[r * 768 + DINNER + d];
            xz[r * 768 + d] = (y + u * Dd) * (z / (1.f + expf(-z)));
        }
    }
}

// ---------------- final layernorm: per-row stats ----------------
__global__ __launch_bounds__(256) void ln_stats_kernel(const float* __restrict__ x,
                                                       float* __restrict__ stats) {
    int r = blockIdx.x * 4 + (threadIdx.x >> 6);
    int lane = threadIdx.x & 63;
    if (r >= RTOT) return;
    float s = 0.f, ss = 0.f;
    for (int c = lane; c < DM; c += 64) {
        float v = x[(size_t)r * DM + c];
        s += v;
        ss += v * v;
    }
#pragma unroll
    for (int o = 32; o > 0; o >>= 1) {
        s += __shfl_down(s, o);
        ss += __shfl_down(ss, o);
    }
    if (lane == 0) {
        float mu = s / (float)DM;
        float var = ss / (float)DM - mu * mu;
        stats[r * 2] = mu;
        stats[r * 2 + 1] = rsqrtf(var + 1e-5f);
    }
}

// ---------------- normalized mean over sequence ----------------
__global__ __launch_bounds__(256) void ln_mean_kernel(const float* __restrict__ x,
                                                      const float* __restrict__ stats,
                                                      const float* __restrict__ nw,
                                                      const float* __restrict__ nb,
                                                      float* __restrict__ out) {
    int idx = blockIdx.x * 256 + threadIdx.x;
    if (idx >= BB * DM) return;
    int c = idx % DM;
    int b = idx / DM;
    float acc = 0.f;
    for (int l = 0; l < NP; l++) {
        size_t r = (size_t)b * NP + l;
        acc += (x[r * DM + c] - stats[r * 2]) * stats[r * 2 + 1];
    }
    out[idx] = acc * (1.f / (float)NP) * nw[c] + nb[c];
}

extern "C" void kernel_launch(void* const* d_in, const int* in_sizes, int n_in,
                              void* d_out, int out_size, void* d_ws, size_t ws_size,
                              hipStream_t stream) {
    const float* img     = (const float*)d_in[0];
    const float* patch_w = (const float*)d_in[1];
    const float* patch_b = (const float*)d_in[2];
    const float* in_w    = (const float*)d_in[3];
    const float* conv_w  = (const float*)d_in[4];
    const float* conv_b  = (const float*)d_in[5];
    const float* xpw     = (const float*)d_in[6];
    const float* dtw     = (const float*)d_in[7];
    const float* dtb     = (const float*)d_in[8];
    const float* A_log   = (const float*)d_in[9];
    const float* Dv      = (const float*)d_in[10];
    const float* outw    = (const float*)d_in[11];
    const float* norm_w  = (const float*)d_in[12];
    const float* norm_b  = (const float*)d_in[13];
    float* out = (float*)d_out;

    float* ws = (float*)d_ws;
    const size_t R = RTOT;
    float* xA     = ws;                  // R*192
    float* xB     = xA + R * DM;         // R*192
    float* xz     = xB + R * DM;         // R*768   (xs | z; y2 overwrites xs half)
    float* xc     = xz + R * 768;        // R*384
    float* proj   = xc + R * DINNER;     // R*44
    float* dtbuf  = proj + R * 44;       // R*384
    float* hEnd   = dtbuf + R * DINNER;  // B*CHUNKS*384*16
    float* prodDA = hEnd + (size_t)BB * CHUNKS * DINNER * DSTATE;   // same size (becomes hInit)
    float* stats  = prodDA + (size_t)BB * CHUNKS * DINNER * DSTATE; // R*2

    // patch embed: im2col + GEMM(+bias)   M=12544, N=192, K=768
    {
        size_t n = R * 768;
        im2col_kernel<<<dim3((unsigned)((n + 255) / 256)), 256, 0, stream>>>(img, xz);
        gemm_tile_kernel<128, 64, 2, 1><<<dim3(DM / 64, RTOT / 128), 256, 0, stream>>>(
            xz, 768, patch_w, xA, patch_b, RTOT, DM, 768);
    }

    float* xin = xA;
    float* xout = xB;
    for (int layer = 0; layer < DEPTH; layer++) {
        const float* in_w_l  = in_w + (size_t)layer * 2 * DINNER * DM;
        const float* conv_wl = conv_w + (size_t)layer * DINNER * DCONV;
        const float* conv_bl = conv_b + (size_t)layer * DINNER;
        const float* xpw_l   = xpw + (size_t)layer * (DTR + 2 * DSTATE) * DINNER;
        const float* dtw_l   = dtw + (size_t)layer * DINNER * DTR;
        const float* dtb_l   = dtb + (size_t)layer * DINNER;
        const float* Alog_l  = A_log + (size_t)layer * DINNER * DSTATE;
        const float* Dv_l    = Dv + (size_t)layer * DINNER;
        const float* outw_l  = outw + (size_t)layer * DM * DINNER;

        // xz = x @ in_w^T   (M=12544, N=768, K=192)
        gemm_tile_kernel<128, 128, 2, 2><<<dim3(768 / 128, RTOT / 128), 256, 0, stream>>>(
            xin, DM, in_w_l, xz, nullptr, RTOT, 2 * DINNER, DM);
        // xc = silu(causal depthwise conv(xs))
        {
            size_t n = R * DINNER;
            conv_silu_kernel<<<dim3((unsigned)((n + 255) / 256)), 256, 0, stream>>>(
                xz, conv_wl, conv_bl, xc);
        }
        // proj = xc @ xpw^T   (M=12544, N=44, K=384)
        gemm_tile_kernel<64, 64, 1, 1><<<dim3(1, RTOT / 64), 256, 0, stream>>>(
            xc, DINNER, xpw_l, proj, nullptr, RTOT, DTR + 2 * DSTATE, DINNER);
        // dt = softplus(proj[:, :12] @ dtw^T + dtb)
        dt_kernel<<<dim3((RTOT * DINNER + 255) / 256), 256, 0, stream>>>(
            proj, dtw_l, dtb_l, dtbuf);
        // chunked scan: A (local), B (combine), C (apply + epilogue -> xz xs-half)
        scanA_kernel<<<dim3(DINNER / 16, CHUNKS, BB), 256, 0, stream>>>(
            xc, proj, dtbuf, Alog_l, hEnd, prodDA);
        scanB_kernel<<<dim3((BB * DINNER * DSTATE + 255) / 256), 256, 0, stream>>>(
            hEnd, prodDA);
        scanC_kernel<<<dim3(DINNER / 16, CHUNKS, BB), 256, 0, stream>>>(
            xc, proj, dtbuf, prodDA, Alog_l, Dv_l, xz);
        // x_next = y2 @ outw^T   (M=12544, N=192, K=384; A = xz with lda=768)
        gemm_tile_kernel<128, 64, 2, 1><<<dim3(DM / 64, RTOT / 128), 256, 0, stream>>>(
            xz, 768, outw_l, xout, nullptr, RTOT, DM, DINNER);

        float* t = xin; xin = xout; xout = t;
    }

    // final layernorm + mean over sequence
    ln_stats_kernel<<<dim3(RTOT / 4), 256, 0, stream>>>(xin, stats);
    ln_mean_kernel<<<dim3((BB * DM + 255) / 256), 256, 0, stream>>>(
        xin, stats, norm_w, norm_b, out);
}

// Round 4
// 6925.200 us; speedup vs baseline: 1.8528x; 1.2008x over previous
//
#include <hip/hip_runtime.h>
#include <hip/hip_bf16.h>
#include <math.h>

#define BB 64
#define IMG 224
#define PP 16
#define CIN 3
#define DM 192
#define DEPTH 24
#define DSTATE 16
#define DINNER 384
#define DTR 12
#define DCONV 4
#define NP 196              // (224/16)^2
#define RTOT (BB * NP)      // 12544 rows
#define CHUNKS 7
#define LC 28               // NP / CHUNKS

// ---------------- im2col for patch embed ----------------
__global__ __launch_bounds__(256) void im2col_kernel(const float* __restrict__ img,
                                                     float* __restrict__ col) {
    size_t idx = (size_t)blockIdx.x * 256 + threadIdx.x;
    if (idx >= (size_t)RTOT * 768) return;
    int t = (int)(idx % 768);
    size_t r = idx / 768;
    int l = (int)(r % NP);
    int b = (int)(r / NP);
    int ph = l / 14, pw = l % 14;
    int ci = t / 256, rem = t % 256;
    int i = rem / 16, j = rem % 16;
    col[idx] = img[(((size_t)b * CIN + ci) * IMG + ph * 16 + i) * IMG + pw * 16 + j];
}

// ---------------- tiled fp32 GEMM: C[M,N] = A[M,K](lda) * B[N,K]^T (+bias) ----------------
template<int BM, int BN, int RM, int RN>
__global__ __launch_bounds__(256) void gemm_tile_kernel(const float* __restrict__ A, int lda,
                                                        const float* __restrict__ Bm,
                                                        float* __restrict__ C,
                                                        const float* __restrict__ bias,
                                                        int M, int N, int K) {
    constexpr int BK = 16;
    constexpr int LDA_S = BM + 4;
    constexpr int LDB_S = BN + 4;
    __shared__ float As[BK * LDA_S];
    __shared__ float Bs[BK * LDB_S];
    const int tid = threadIdx.x;
    const int tr = tid / 16, tc = tid % 16;
    const int row0 = blockIdx.y * BM, col0 = blockIdx.x * BN;
    const int lrow = tid / 4;     // 0..63, + g*64
    const int lc4  = tid % 4;     // which float4 along k

    float acc[RM * 4][RN * 4] = {};
    float4 aReg[RM], bReg[RN];

    auto loadG = [&](int k0) {
#pragma unroll
        for (int g = 0; g < RM; g++) {
            int row = g * 64 + lrow;
            aReg[g] = *(const float4*)&A[(size_t)(row0 + row) * lda + k0 + lc4 * 4];
        }
#pragma unroll
        for (int g = 0; g < RN; g++) {
            int n = g * 64 + lrow;
            if (col0 + n < N)
                bReg[g] = *(const float4*)&Bm[(size_t)(col0 + n) * K + k0 + lc4 * 4];
            else
                bReg[g] = make_float4(0.f, 0.f, 0.f, 0.f);
        }
    };
    auto storeLDS = [&]() {
#pragma unroll
        for (int g = 0; g < RM; g++) {
            int row = g * 64 + lrow;
            As[(lc4 * 4 + 0) * LDA_S + row] = aReg[g].x;
            As[(lc4 * 4 + 1) * LDA_S + row] = aReg[g].y;
            As[(lc4 * 4 + 2) * LDA_S + row] = aReg[g].z;
            As[(lc4 * 4 + 3) * LDA_S + row] = aReg[g].w;
        }
#pragma unroll
        for (int g = 0; g < RN; g++) {
            int n = g * 64 + lrow;
            Bs[(lc4 * 4 + 0) * LDB_S + n] = bReg[g].x;
            Bs[(lc4 * 4 + 1) * LDB_S + n] = bReg[g].y;
            Bs[(lc4 * 4 + 2) * LDB_S + n] = bReg[g].z;
            Bs[(lc4 * 4 + 3) * LDB_S + n] = bReg[g].w;
        }
    };

    loadG(0);
    storeLDS();
    __syncthreads();
    for (int k0 = BK;; k0 += BK) {
        const bool has_next = (k0 < K);
        if (has_next) loadG(k0);      // global loads in flight during compute
#pragma unroll
        for (int k = 0; k < BK; k++) {
            float a[RM * 4], b[RN * 4];
#pragma unroll
            for (int g = 0; g < RM; g++)
                *(float4*)&a[g * 4] = *(const float4*)&As[k * LDA_S + g * 64 + tr * 4];
#pragma unroll
            for (int g = 0; g < RN; g++)
                *(float4*)&b[g * 4] = *(const float4*)&Bs[k * LDB_S + g * 64 + tc * 4];
#pragma unroll
            for (int i = 0; i < RM * 4; i++)
#pragma unroll
                for (int j = 0; j < RN * 4; j++)
                    acc[i][j] = fmaf(a[i], b[j], acc[i][j]);
        }
        if (!has_next) break;
        __syncthreads();
        storeLDS();
        __syncthreads();
    }

#pragma unroll
    for (int gi = 0; gi < RM; gi++)
#pragma unroll
        for (int i = 0; i < 4; i++) {
            int gm = row0 + gi * 64 + tr * 4 + i;
#pragma unroll
            for (int gj = 0; gj < RN; gj++) {
                int gn = col0 + gj * 64 + tc * 4;
                if (gn + 3 < N) {
                    float4 v;
                    v.x = acc[gi * 4 + i][gj * 4 + 0];
                    v.y = acc[gi * 4 + i][gj * 4 + 1];
                    v.z = acc[gi * 4 + i][gj * 4 + 2];
                    v.w = acc[gi * 4 + i][gj * 4 + 3];
                    if (bias) {
                        float4 bv = *(const float4*)&bias[gn];
                        v.x += bv.x; v.y += bv.y; v.z += bv.z; v.w += bv.w;
                    }
                    *(float4*)&C[(size_t)gm * N + gn] = v;
                }
            }
        }
}

// ---------------- causal depthwise conv (DCONV=4) + SiLU ----------------
__global__ __launch_bounds__(256) void conv_silu_kernel(const float* __restrict__ xz,
                                                        const float* __restrict__ cw,
                                                        const float* __restrict__ cb,
                                                        float* __restrict__ xc) {
    size_t idx = (size_t)blockIdx.x * 256 + threadIdx.x;
    if (idx >= (size_t)RTOT * DINNER) return;
    int e = (int)(idx % DINNER);
    size_t r = idx / DINNER;
    int l = (int)(r % NP);
    size_t b = r / NP;
    const float* w = cw + (size_t)e * DCONV;
    float acc = cb[e];
#pragma unroll
    for (int k = 0; k < DCONV; k++) {
        int ls = l + k - (DCONV - 1);
        if (ls >= 0) acc += xz[(b * NP + ls) * 768 + e] * w[k];
    }
    xc[idx] = acc / (1.f + expf(-acc));   // silu
}

// ---------------- dt projection + softplus ----------------
__global__ __launch_bounds__(256) void dt_kernel(const float* __restrict__ proj,
                                                 const float* __restrict__ dtw,
                                                 const float* __restrict__ dtb,
                                                 float* __restrict__ dt) {
    int idx = blockIdx.x * 256 + threadIdx.x;
    if (idx >= RTOT * DINNER) return;
    int d = idx % DINNER;
    size_t r = (size_t)idx / DINNER;
    const float* pr = proj + r * 44;
    const float* w = dtw + (size_t)d * DTR;
    float acc = dtb[d];
#pragma unroll
    for (int k = 0; k < DTR; k++) acc += pr[k] * w[k];
    dt[idx] = (acc > 20.f) ? acc : log1pf(expf(acc));   // softplus
}

// ---------------- chunked selective scan: lane owns (b,d), 16 states in regs ----------------
// Pass A: local scan from h=0; record hEnd[16] and prod(dA)[16] (float4 stores).
__global__ __launch_bounds__(128) void scanA_kernel(const float* __restrict__ xc,
                                                    const float* __restrict__ proj,
                                                    const float* __restrict__ dt,
                                                    const float* __restrict__ A_log,
                                                    float* __restrict__ hEnd,
                                                    float* __restrict__ prodDA) {
    int d = blockIdx.x * 128 + threadIdx.x;       // grid.x = 3
    int c = blockIdx.y, b = blockIdx.z;
    float a[DSTATE], h[DSTATE], p[DSTATE];
#pragma unroll
    for (int s = 0; s < DSTATE; s++) {
        a[s] = -expf(A_log[(size_t)d * DSTATE + s]);
        h[s] = 0.f;
        p[s] = 1.f;
    }
    size_t rbase = (size_t)b * NP + (size_t)c * LC;
    for (int l = 0; l < LC; l++) {
        size_t r = rbase + l;
        float dtv = dt[r * DINNER + d];
        float du = dtv * xc[r * DINNER + d];
        const float* pb = proj + r * 44 + DTR;    // wave-uniform
        float Bv[DSTATE];
        *(float4*)&Bv[0]  = *(const float4*)&pb[0];
        *(float4*)&Bv[4]  = *(const float4*)&pb[4];
        *(float4*)&Bv[8]  = *(const float4*)&pb[8];
        *(float4*)&Bv[12] = *(const float4*)&pb[12];
#pragma unroll
        for (int s = 0; s < DSTATE; s++) {
            float dA = expf(dtv * a[s]);
            h[s] = h[s] * dA + du * Bv[s];
            p[s] *= dA;
        }
    }
    float* he = hEnd   + (((size_t)b * CHUNKS + c) * DINNER + d) * DSTATE;
    float* pd = prodDA + (((size_t)b * CHUNKS + c) * DINNER + d) * DSTATE;
#pragma unroll
    for (int g = 0; g < 4; g++) {
        *(float4*)&he[g * 4] = *(float4*)&h[g * 4];
        *(float4*)&pd[g * 4] = *(float4*)&p[g * 4];
    }
}

// Pass B: sequential combine over chunks; writes hInit(c) IN PLACE over prodDA.
__global__ __launch_bounds__(256) void scanB_kernel(const float* __restrict__ hEnd,
                                                    float* __restrict__ prodDA) {
    int idx = blockIdx.x * 256 + threadIdx.x;
    if (idx >= BB * DINNER * DSTATE) return;
    int b = idx / (DINNER * DSTATE);
    int rem = idx % (DINNER * DSTATE);
    float run = 0.f;
    for (int c = 0; c < CHUNKS; c++) {
        size_t off = ((size_t)b * CHUNKS + c) * (DINNER * DSTATE) + rem;
        float p = prodDA[off];
        float e = hEnd[off];
        prodDA[off] = run;          // hInit for chunk c
        run = run * p + e;
    }
}

// Pass C: rerun local scan from hInit; y = sum_s h[s]*C[s]; fused (y+u*D)*silu(z).
// Writes y2 into xz cols [0,384); reads z from cols [384,768).
__global__ __launch_bounds__(128) void scanC_kernel(const float* __restrict__ xc,
                                                    const float* __restrict__ proj,
                                                    const float* __restrict__ dt,
                                                    const float* __restrict__ hInit,
                                                    const float* __restrict__ A_log,
                                                    const float* __restrict__ Dv,
                                                    float* __restrict__ xz) {
    int d = blockIdx.x * 128 + threadIdx.x;       // grid.x = 3
    int c = blockIdx.y, b = blockIdx.z;
    float a[DSTATE], h[DSTATE];
#pragma unroll
    for (int s = 0; s < DSTATE; s++)
        a[s] = -expf(A_log[(size_t)d * DSTATE + s]);
    const float* hi = hInit + (((size_t)b * CHUNKS + c) * DINNER + d) * DSTATE;
#pragma unroll
    for (int g = 0; g < 4; g++)
        *(float4*)&h[g * 4] = *(const float4*)&hi[g * 4];
    float Dd = Dv[d];
    size_t rbase = (size_t)b * NP + (size_t)c * LC;
    for (int l = 0; l < LC; l++) {
        size_t r = rbase + l;
        float dtv = dt[r * DINNER + d];
        float u = xc[r * DINNER + d];
        float du = dtv * u;
        const float* pb = proj + r * 44 + DTR;              // wave-uniform
        const float* pc = proj + r * 44 + DTR + DSTATE;
        float Bv[DSTATE], Cv[DSTATE];
        *(float4*)&Bv[0]  = *(const float4*)&pb[0];
        *(float4*)&Bv[4]  = *(const float4*)&pb[4];
        *(float4*)&Bv[8]  = *(const float4*)&pb[8];
        *(float4*)&Bv[12] = *(const float4*)&pb[12];
        *(float4*)&Cv[0]  = *(const float4*)&pc[0];
        *(float4*)&Cv[4]  = *(const float4*)&pc[4];
        *(float4*)&Cv[8]  = *(const float4*)&pc[8];
        *(float4*)&Cv[12] = *(const float4*)&pc[12];
        float y = 0.f;
#pragma unroll
        for (int s = 0; s < DSTATE; s++) {
            float dA = expf(dtv * a[s]);
            h[s] = h[s] * dA + du * Bv[s];
            y = fmaf(h[s], Cv[s], y);
        }
        float z = xz[r * 768 + DINNER + d];
        xz[r * 768 + d] = (y + u * Dd) * (z / (1.f + expf(-z)));
    }
}

// ---------------- final layernorm: per-row stats ----------------
__global__ __launch_bounds__(256) void ln_stats_kernel(const float* __restrict__ x,
                                                       float* __restrict__ stats) {
    int r = blockIdx.x * 4 + (threadIdx.x >> 6);
    int lane = threadIdx.x & 63;
    if (r >= RTOT) return;
    float s = 0.f, ss = 0.f;
    for (int c = lane; c < DM; c += 64) {
        float v = x[(size_t)r * DM + c];
        s += v;
        ss += v * v;
    }
#pragma unroll
    for (int o = 32; o > 0; o >>= 1) {
        s += __shfl_down(s, o);
        ss += __shfl_down(ss, o);
    }
    if (lane == 0) {
        float mu = s / (float)DM;
        float var = ss / (float)DM - mu * mu;
        stats[r * 2] = mu;
        stats[r * 2 + 1] = rsqrtf(var + 1e-5f);
    }
}

// ---------------- normalized mean over sequence ----------------
__global__ __launch_bounds__(256) void ln_mean_kernel(const float* __restrict__ x,
                                                      const float* __restrict__ stats,
                                                      const float* __restrict__ nw,
                                                      const float* __restrict__ nb,
                                                      float* __restrict__ out) {
    int idx = blockIdx.x * 256 + threadIdx.x;
    if (idx >= BB * DM) return;
    int c = idx % DM;
    int b = idx / DM;
    float acc = 0.f;
    for (int l = 0; l < NP; l++) {
        size_t r = (size_t)b * NP + l;
        acc += (x[r * DM + c] - stats[r * 2]) * stats[r * 2 + 1];
    }
    out[idx] = acc * (1.f / (float)NP) * nw[c] + nb[c];
}

extern "C" void kernel_launch(void* const* d_in, const int* in_sizes, int n_in,
                              void* d_out, int out_size, void* d_ws, size_t ws_size,
                              hipStream_t stream) {
    const float* img     = (const float*)d_in[0];
    const float* patch_w = (const float*)d_in[1];
    const float* patch_b = (const float*)d_in[2];
    const float* in_w    = (const float*)d_in[3];
    const float* conv_w  = (const float*)d_in[4];
    const float* conv_b  = (const float*)d_in[5];
    const float* xpw     = (const float*)d_in[6];
    const float* dtw     = (const float*)d_in[7];
    const float* dtb     = (const float*)d_in[8];
    const float* A_log   = (const float*)d_in[9];
    const float* Dv      = (const float*)d_in[10];
    const float* outw    = (const float*)d_in[11];
    const float* norm_w  = (const float*)d_in[12];
    const float* norm_b  = (const float*)d_in[13];
    float* out = (float*)d_out;

    float* ws = (float*)d_ws;
    const size_t R = RTOT;
    float* xA     = ws;                  // R*192
    float* xB     = xA + R * DM;         // R*192
    float* xz     = xB + R * DM;         // R*768   (xs | z; y2 overwrites xs half)
    float* xc     = xz + R * 768;        // R*384
    float* proj   = xc + R * DINNER;     // R*44
    float* dtbuf  = proj + R * 44;       // R*384
    float* hEnd   = dtbuf + R * DINNER;  // B*CHUNKS*384*16
    float* prodDA = hEnd + (size_t)BB * CHUNKS * DINNER * DSTATE;   // same size (becomes hInit)
    float* stats  = prodDA + (size_t)BB * CHUNKS * DINNER * DSTATE; // R*2

    // patch embed: im2col + GEMM(+bias)   M=12544, N=192, K=768
    {
        size_t n = R * 768;
        im2col_kernel<<<dim3((unsigned)((n + 255) / 256)), 256, 0, stream>>>(img, xz);
        gemm_tile_kernel<128, 64, 2, 1><<<dim3(DM / 64, RTOT / 128), 256, 0, stream>>>(
            xz, 768, patch_w, xA, patch_b, RTOT, DM, 768);
    }

    float* xin = xA;
    float* xout = xB;
    for (int layer = 0; layer < DEPTH; layer++) {
        const float* in_w_l  = in_w + (size_t)layer * 2 * DINNER * DM;
        const float* conv_wl = conv_w + (size_t)layer * DINNER * DCONV;
        const float* conv_bl = conv_b + (size_t)layer * DINNER;
        const float* xpw_l   = xpw + (size_t)layer * (DTR + 2 * DSTATE) * DINNER;
        const float* dtw_l   = dtw + (size_t)layer * DINNER * DTR;
        const float* dtb_l   = dtb + (size_t)layer * DINNER;
        const float* Alog_l  = A_log + (size_t)layer * DINNER * DSTATE;
        const float* Dv_l    = Dv + (size_t)layer * DINNER;
        const float* outw_l  = outw + (size_t)layer * DM * DINNER;

        // xz = x @ in_w^T   (M=12544, N=768, K=192)
        gemm_tile_kernel<128, 128, 2, 2><<<dim3(768 / 128, RTOT / 128), 256, 0, stream>>>(
            xin, DM, in_w_l, xz, nullptr, RTOT, 2 * DINNER, DM);
        // xc = silu(causal depthwise conv(xs))
        {
            size_t n = R * DINNER;
            conv_silu_kernel<<<dim3((unsigned)((n + 255) / 256)), 256, 0, stream>>>(
                xz, conv_wl, conv_bl, xc);
        }
        // proj = xc @ xpw^T   (M=12544, N=44, K=384)
        gemm_tile_kernel<64, 64, 1, 1><<<dim3(1, RTOT / 64), 256, 0, stream>>>(
            xc, DINNER, xpw_l, proj, nullptr, RTOT, DTR + 2 * DSTATE, DINNER);
        // dt = softplus(proj[:, :12] @ dtw^T + dtb)
        dt_kernel<<<dim3((RTOT * DINNER + 255) / 256), 256, 0, stream>>>(
            proj, dtw_l, dtb_l, dtbuf);
        // chunked scan: A (local), B (combine), C (apply + epilogue -> xz xs-half)
        scanA_kernel<<<dim3(3, CHUNKS, BB), 128, 0, stream>>>(
            xc, proj, dtbuf, Alog_l, hEnd, prodDA);
        scanB_kernel<<<dim3((BB * DINNER * DSTATE + 255) / 256), 256, 0, stream>>>(
            hEnd, prodDA);
        scanC_kernel<<<dim3(3, CHUNKS, BB), 128, 0, stream>>>(
            xc, proj, dtbuf, prodDA, Alog_l, Dv_l, xz);
        // x_next = y2 @ outw^T   (M=12544, N=192, K=384; A = xz with lda=768)
        gemm_tile_kernel<128, 64, 2, 1><<<dim3(DM / 64, RTOT / 128), 256, 0, stream>>>(
            xz, 768, outw_l, xout, nullptr, RTOT, DM, DINNER);

        float* t = xin; xin = xout; xout = t;
    }

    // final layernorm + mean over sequence
    ln_stats_kernel<<<dim3(RTOT / 4), 256, 0, stream>>>(xin, stats);
    ln_mean_kernel<<<dim3((BB * DM + 255) / 256), 256, 0, stream>>>(
        xin, stats, norm_w, norm_b, out);
}